// Round 2
// baseline (137.834 us; speedup 1.0000x reference)
//
#include <hip/hip_runtime.h>

// RedistributionNetwork: 128 sequential tridiagonal layers on [256,1024] f32 state.
// h'[i] = a[i]*h[i-1] + b[i]*h[i] + c[i]*h[i+1], where a[l][i]=W[l,i,i-1],
// b[l][i]=W[l,i,i], c[l][i]=W[l,i,i+1]; all off-band entries of W are exactly 0.

#define NXL 128   // layers
#define NYP 1024  // state width
#define NB  256   // batch
#define RPL 16    // rows per lane: 64 lanes * 16 = 1024

// ---------------- kernel 1: band extraction ----------------
// W: [NXL][NYP][NYP] f32  ->  wb: [NXL][3][NYP] f32 (a, b, c rows per layer)
__global__ __launch_bounds__(256) void extract_band(const float* __restrict__ W,
                                                    float* __restrict__ wb) {
    int idx = blockIdx.x * 256 + threadIdx.x;   // 0 .. NXL*NYP-1
    int l = idx >> 10;
    int i = idx & (NYP - 1);
    const float* row = W + ((size_t)l << 20) + ((size_t)i << 10);
    // nontemporal: W lines are dead after this read; don't evict the band from L2
    float a = (i > 0)       ? __builtin_nontemporal_load(row + i - 1) : 0.0f;
    float b = __builtin_nontemporal_load(row + i);
    float c = (i < NYP - 1) ? __builtin_nontemporal_load(row + i + 1) : 0.0f;
    float* dst = wb + (size_t)l * (3 * NYP);
    dst[i]           = a;
    dst[NYP + i]     = b;
    dst[2 * NYP + i] = c;
}

// ---------------- kernel 2: banded propagation ----------------
// One wave per batch element; lane owns 16 consecutive rows in registers.
// Weights: 4 named register buffers, software-pipelined ~3 steps ahead.

struct WBuf {
    float4 a[4], b[4], c[4];   // 16 rows' worth of each diagonal
};

__device__ __forceinline__ float comp(const float4& v, int k) {
    // k is compile-time constant at every call site (full unroll)
    return k == 0 ? v.x : k == 1 ? v.y : k == 2 ? v.z : v.w;
}

__device__ __forceinline__ void load_layer(const float* __restrict__ wb, int layer,
                                           int i0, WBuf& w) {
    const float* wl = wb + (size_t)layer * (3 * NYP);
#pragma unroll
    for (int q = 0; q < 4; ++q) {
        w.a[q] = *reinterpret_cast<const float4*>(wl + i0 + 4 * q);
        w.b[q] = *reinterpret_cast<const float4*>(wl + NYP + i0 + 4 * q);
        w.c[q] = *reinterpret_cast<const float4*>(wl + 2 * NYP + i0 + 4 * q);
    }
}

__device__ __forceinline__ void step(float (&h)[RPL], const WBuf& w) {
    // neighbor halo via in-wave shuffles; lane-edge garbage is multiplied by
    // the exact-zero boundary weights a[0] / c[1023]
    float left  = __shfl_up(h[RPL - 1], 1);
    float right = __shfl_down(h[0], 1);
    float carry = left;   // carry = old h[j-1]
#pragma unroll
    for (int j = 0; j < RPL; ++j) {
        float aj = comp(w.a[j >> 2], j & 3);
        float bj = comp(w.b[j >> 2], j & 3);
        float cj = comp(w.c[j >> 2], j & 3);
        float orig = h[j];
        float hp = (j == RPL - 1) ? right : h[j + 1];
        h[j] = fmaf(aj, carry, fmaf(bj, orig, cj * hp));
        carry = orig;
    }
}

__global__ __launch_bounds__(64) void propagate(const float* __restrict__ x,
                                                const float* __restrict__ wb,
                                                float* __restrict__ out) {
    const int b = blockIdx.x;
    const int lane = threadIdx.x & 63;
    const int i0 = lane * RPL;

    float h[RPL];
    const float4* xb = reinterpret_cast<const float4*>(x + (size_t)b * NYP + i0);
#pragma unroll
    for (int q = 0; q < 4; ++q) {
        float4 v = xb[q];
        h[4 * q + 0] = v.x; h[4 * q + 1] = v.y;
        h[4 * q + 2] = v.z; h[4 * q + 3] = v.w;
    }

    // 4 named buffers (no arrays of buffers -> no runtime indexing -> no scratch)
    WBuf B0, B1, B2, B3;
    load_layer(wb, 0, i0, B0);
    load_layer(wb, 1, i0, B1);
    load_layer(wb, 2, i0, B2);

#pragma unroll 1
    for (int l = 0; l < NXL; l += 4) {
        // issue load -> consume a different buffer; prefetch distance ~3 steps
        load_layer(wb, min(l + 3, NXL - 1), i0, B3);
        step(h, B0);
        load_layer(wb, min(l + 4, NXL - 1), i0, B0);
        step(h, B1);
        load_layer(wb, min(l + 5, NXL - 1), i0, B1);
        step(h, B2);
        load_layer(wb, min(l + 6, NXL - 1), i0, B2);
        step(h, B3);
    }

    float4* ob = reinterpret_cast<float4*>(out + (size_t)b * NYP + i0);
#pragma unroll
    for (int q = 0; q < 4; ++q) {
        ob[q] = make_float4(h[4 * q + 0], h[4 * q + 1], h[4 * q + 2], h[4 * q + 3]);
    }
}

// ---------------- fallback: direct scattered weight reads (if ws too small) ----------------
__global__ __launch_bounds__(64) void propagate_direct(const float* __restrict__ x,
                                                       const float* __restrict__ W,
                                                       float* __restrict__ out) {
    const int b = blockIdx.x;
    const int lane = threadIdx.x & 63;
    const int i0 = lane * RPL;

    float h[RPL];
    const float4* xb = reinterpret_cast<const float4*>(x + (size_t)b * NYP + i0);
#pragma unroll
    for (int q = 0; q < 4; ++q) {
        float4 v = xb[q];
        h[4 * q + 0] = v.x; h[4 * q + 1] = v.y;
        h[4 * q + 2] = v.z; h[4 * q + 3] = v.w;
    }

#pragma unroll 1
    for (int l = 0; l < NXL; ++l) {
        const float* Wl = W + ((size_t)l << 20);
        WBuf w;
#pragma unroll
        for (int q = 0; q < 4; ++q) {
            float a0[4], b0[4], c0[4];
#pragma unroll
            for (int k = 0; k < 4; ++k) {
                int i = i0 + 4 * q + k;
                const float* row = Wl + ((size_t)i << 10);
                a0[k] = (i > 0)       ? row[i - 1] : 0.0f;
                b0[k] = row[i];
                c0[k] = (i < NYP - 1) ? row[i + 1] : 0.0f;
            }
            w.a[q] = make_float4(a0[0], a0[1], a0[2], a0[3]);
            w.b[q] = make_float4(b0[0], b0[1], b0[2], b0[3]);
            w.c[q] = make_float4(c0[0], c0[1], c0[2], c0[3]);
        }
        step(h, w);
    }

    float4* ob = reinterpret_cast<float4*>(out + (size_t)b * NYP + i0);
#pragma unroll
    for (int q = 0; q < 4; ++q) {
        ob[q] = make_float4(h[4 * q + 0], h[4 * q + 1], h[4 * q + 2], h[4 * q + 3]);
    }
}

extern "C" void kernel_launch(void* const* d_in, const int* in_sizes, int n_in,
                              void* d_out, int out_size, void* d_ws, size_t ws_size,
                              hipStream_t stream) {
    const float* x = (const float*)d_in[0];   // [256,1024] f32
    const float* W = (const float*)d_in[1];   // [128,1024,1024] f32
    float* out = (float*)d_out;               // [256,1024] f32

    const size_t need = (size_t)NXL * 3 * NYP * sizeof(float);  // 1.5 MB
    if (ws_size >= need) {
        float* wbp = (float*)d_ws;
        extract_band<<<(NXL * NYP) / 256, 256, 0, stream>>>(W, wbp);
        propagate<<<NB, 64, 0, stream>>>(x, wbp, out);
    } else {
        propagate_direct<<<NB, 64, 0, stream>>>(x, W, out);
    }
}

// Round 3
// 45.546 us; speedup vs baseline: 3.0263x; 3.0263x over previous
//
#include <hip/hip_runtime.h>

// RedistributionNetwork: 128 sequential tridiagonal layers on [256,1024] f32 state.
// h'[i] = a[i]*h[i-1] + b[i]*h[i] + c[i]*h[i+1], where a[l][i]=W[l,i,i-1],
// b[l][i]=W[l,i,i], c[l][i]=W[l,i,i+1]; all off-band entries of W are exactly 0
// (band_mask), so a[l][0]==0 and c[l][1023]==0 exactly -> edge garbage is annihilated.

#define NXL 128   // layers
#define NYP 1024  // state width
#define NB  256   // batch

// ---------------- kernel 1: band extraction ----------------
// W: [NXL][NYP][NYP] f32  ->  wb: [NXL][3][NYP] f32 (a, b, c rows per layer)
__global__ __launch_bounds__(256) void extract_band(const float* __restrict__ W,
                                                    float* __restrict__ wb) {
    int idx = blockIdx.x * 256 + threadIdx.x;   // 0 .. NXL*NYP-1
    int l = idx >> 10;
    int i = idx & (NYP - 1);
    const float* row = W + ((size_t)l << 20) + ((size_t)i << 10);
    float a = (i > 0)       ? row[i - 1] : 0.0f;   // W[l,i,i-1]
    float b = row[i];                               // W[l,i,i]
    float c = (i < NYP - 1) ? row[i + 1] : 0.0f;   // W[l,i,i+1]
    float* dst = wb + (size_t)l * (3 * NYP);
    dst[i]           = a;
    dst[NYP + i]     = b;
    dst[2 * NYP + i] = c;
}

// ---------------- kernel 2: banded propagation ----------------
// 256 blocks (one per batch element) x 256 threads (4 waves, one per SIMD).
// Lane owns 4 consecutive rows: row base = tid*4. Intra-wave halo via shuffles;
// inter-wave halo via parity-double-buffered LDS, ONE __syncthreads per layer.
// Weights: 3 float4 per lane per layer, software-pipelined 3 layers ahead
// (4 named buffers, 48 VGPR total -> no spill risk).

struct W4 { float4 a, b, c; };

__device__ __forceinline__ void load_w(const float* __restrict__ wb, int layer,
                                       int r0, W4& w) {
    const float* wl = wb + (size_t)layer * (3 * NYP);
    w.a = *reinterpret_cast<const float4*>(wl + r0);
    w.b = *reinterpret_cast<const float4*>(wl + NYP + r0);
    w.c = *reinterpret_cast<const float4*>(wl + 2 * NYP + r0);
}

// hal: [parity][wave][0]=first-row h, [1]=last-row h of that wave's 256-row span
__device__ __forceinline__ void layer_step(float (&h)[4], const W4& w,
                                           float (*cur)[2], float (*nxt)[2],
                                           int wv, int lane) {
    // halo reads (cur buffer valid per previous barrier); same-address within a
    // wave -> LDS broadcast, no bank conflict
    float ldsL = cur[(wv + 3) & 3][1];
    float ldsR = cur[(wv + 1) & 3][0];
    float left  = __shfl_up(h[3], 1);    // prev lane's last row
    float right = __shfl_down(h[0], 1);  // next lane's first row
    if (lane == 0)  left  = ldsL;        // wave 0: a[0]==0 kills it exactly
    if (lane == 63) right = ldsR;        // wave 3: c[1023]==0 kills it exactly
    float n0 = fmaf(w.a.x, left, fmaf(w.b.x, h[0], w.c.x * h[1]));
    float n1 = fmaf(w.a.y, h[0], fmaf(w.b.y, h[1], w.c.y * h[2]));
    float n2 = fmaf(w.a.z, h[1], fmaf(w.b.z, h[2], w.c.z * h[3]));
    float n3 = fmaf(w.a.w, h[2], fmaf(w.b.w, h[3], w.c.w * right));
    h[0] = n0; h[1] = n1; h[2] = n2; h[3] = n3;
    // publish next layer's halo into the other parity buffer
    if (lane == 0)  nxt[wv][0] = h[0];
    if (lane == 63) nxt[wv][1] = h[3];
    __syncthreads();   // one barrier per layer
}

__global__ __launch_bounds__(256) void propagate(const float* __restrict__ x,
                                                 const float* __restrict__ wb,
                                                 float* __restrict__ out) {
    __shared__ float hal[2][4][2];
    const int b    = blockIdx.x;
    const int tid  = threadIdx.x;
    const int wv   = tid >> 6;
    const int lane = tid & 63;
    const int r0   = tid * 4;   // global row base for this lane

    float h[4];
    {
        float4 v = *reinterpret_cast<const float4*>(x + (size_t)b * NYP + r0);
        h[0] = v.x; h[1] = v.y; h[2] = v.z; h[3] = v.w;
    }

    W4 A, B, C, D;
    load_w(wb, 0, r0, A);
    load_w(wb, 1, r0, B);
    load_w(wb, 2, r0, C);

    // prologue: publish layer-0 halo
    if (lane == 0)  hal[0][wv][0] = h[0];
    if (lane == 63) hal[0][wv][1] = h[3];
    __syncthreads();

#pragma unroll 1
    for (int l = 0; l < NXL; l += 4) {   // parities per unrolled body: 0,1,0,1
        load_w(wb, (l + 3 < NXL) ? l + 3 : NXL - 1, r0, D);
        layer_step(h, A, hal[0], hal[1], wv, lane);
        load_w(wb, (l + 4 < NXL) ? l + 4 : NXL - 1, r0, A);
        layer_step(h, B, hal[1], hal[0], wv, lane);
        load_w(wb, (l + 5 < NXL) ? l + 5 : NXL - 1, r0, B);
        layer_step(h, C, hal[0], hal[1], wv, lane);
        load_w(wb, (l + 6 < NXL) ? l + 6 : NXL - 1, r0, C);
        layer_step(h, D, hal[1], hal[0], wv, lane);
    }

    *reinterpret_cast<float4*>(out + (size_t)b * NYP + r0) =
        make_float4(h[0], h[1], h[2], h[3]);
}

// ---------------- fallback: direct scattered weight reads (if ws too small) ----------------
__global__ __launch_bounds__(256) void propagate_direct(const float* __restrict__ x,
                                                        const float* __restrict__ W,
                                                        float* __restrict__ out) {
    __shared__ float hal[2][4][2];
    const int b    = blockIdx.x;
    const int tid  = threadIdx.x;
    const int wv   = tid >> 6;
    const int lane = tid & 63;
    const int r0   = tid * 4;

    float h[4];
    {
        float4 v = *reinterpret_cast<const float4*>(x + (size_t)b * NYP + r0);
        h[0] = v.x; h[1] = v.y; h[2] = v.z; h[3] = v.w;
    }

    if (lane == 0)  hal[0][wv][0] = h[0];
    if (lane == 63) hal[0][wv][1] = h[3];
    __syncthreads();

#pragma unroll 1
    for (int l = 0; l < NXL; ++l) {
        const float* Wl = W + ((size_t)l << 20);
        W4 w;
        float t[3][4];
#pragma unroll
        for (int k = 0; k < 4; ++k) {
            int i = r0 + k;
            const float* row = Wl + ((size_t)i << 10);
            t[0][k] = (i > 0)       ? row[i - 1] : 0.0f;
            t[1][k] = row[i];
            t[2][k] = (i < NYP - 1) ? row[i + 1] : 0.0f;
        }
        w.a = make_float4(t[0][0], t[0][1], t[0][2], t[0][3]);
        w.b = make_float4(t[1][0], t[1][1], t[1][2], t[1][3]);
        w.c = make_float4(t[2][0], t[2][1], t[2][2], t[2][3]);
        if (l & 1) layer_step(h, w, hal[1], hal[0], wv, lane);
        else       layer_step(h, w, hal[0], hal[1], wv, lane);
    }

    *reinterpret_cast<float4*>(out + (size_t)b * NYP + r0) =
        make_float4(h[0], h[1], h[2], h[3]);
}

extern "C" void kernel_launch(void* const* d_in, const int* in_sizes, int n_in,
                              void* d_out, int out_size, void* d_ws, size_t ws_size,
                              hipStream_t stream) {
    const float* x = (const float*)d_in[0];   // [256,1024] f32
    const float* W = (const float*)d_in[1];   // [128,1024,1024] f32
    float* out = (float*)d_out;               // [256,1024] f32

    const size_t need = (size_t)NXL * 3 * NYP * sizeof(float);  // 1.5 MB
    if (ws_size >= need) {
        float* wbp = (float*)d_ws;
        extract_band<<<(NXL * NYP) / 256, 256, 0, stream>>>(W, wbp);
        propagate<<<NB, 256, 0, stream>>>(x, wbp, out);
    } else {
        propagate_direct<<<NB, 256, 0, stream>>>(x, W, out);
    }
}

// Round 4
// 45.070 us; speedup vs baseline: 3.0582x; 1.0106x over previous
//
#include <hip/hip_runtime.h>

// RedistributionNetwork: 128 sequential tridiagonal layers on [256,1024] f32 state.
// h'[i] = a[i]*h[i-1] + b[i]*h[i] + c[i]*h[i+1], where a[l][i]=W[l,i,i-1],
// b[l][i]=W[l,i,i], c[l][i]=W[l,i,i+1]; all off-band entries of W are exactly 0
// (band_mask), so a[l][0]==0 and c[l][1023]==0 exactly -> edge garbage is annihilated.

#define NXL 128   // layers
#define NYP 1024  // state width
#define NB  256   // batch

// ---------------- kernel 1: band extraction ----------------
// W: [NXL][NYP][NYP] f32  ->  wb: [NXL][3][NYP] f32 (a, b, c rows per layer)
__global__ __launch_bounds__(256) void extract_band(const float* __restrict__ W,
                                                    float* __restrict__ wb) {
    int idx = blockIdx.x * 256 + threadIdx.x;   // 0 .. NXL*NYP-1
    int l = idx >> 10;
    int i = idx & (NYP - 1);
    const float* row = W + ((size_t)l << 20) + ((size_t)i << 10);
    float a = (i > 0)       ? row[i - 1] : 0.0f;   // W[l,i,i-1]
    float b = row[i];                               // W[l,i,i]
    float c = (i < NYP - 1) ? row[i + 1] : 0.0f;   // W[l,i,i+1]
    float* dst = wb + (size_t)l * (3 * NYP);
    dst[i]           = a;
    dst[NYP + i]     = b;
    dst[2 * NYP + i] = c;
}

// ---------------- kernel 2: banded propagation ----------------
// 256 blocks (one per batch element) x 256 threads (4 waves, one per SIMD).
// Lane owns 4 consecutive rows (base = tid*4). Intra-wave halo via shuffles;
// inter-wave halo via parity-double-buffered LDS with ONE LDS-only barrier per
// layer: s_waitcnt lgkmcnt(0) + raw s_barrier. Crucially this does NOT drain
// vmcnt, so the 3-layer-ahead weight prefetch stays in flight across barriers
// (a __syncthreads here would force vmcnt(0) every layer and expose full L2
// latency per layer — measured as the round-3 regression vs model).

struct W4 { float4 a, b, c; };

__device__ __forceinline__ void load_w(const float* __restrict__ wb, int layer,
                                       int r0, W4& w) {
    const float* wl = wb + (size_t)layer * (3 * NYP);
    w.a = *reinterpret_cast<const float4*>(wl + r0);
    w.b = *reinterpret_cast<const float4*>(wl + NYP + r0);
    w.c = *reinterpret_cast<const float4*>(wl + 2 * NYP + r0);
}

// LDS-only barrier: drain LDS ops, leave global loads in flight.
__device__ __forceinline__ void lds_barrier() {
    asm volatile("s_waitcnt lgkmcnt(0)" ::: "memory");
    __builtin_amdgcn_s_barrier();
}

// hal: [parity][wave][0]=first-row h, [1]=last-row h of that wave's 256-row span
__device__ __forceinline__ void layer_step(float (&h)[4], const W4& w,
                                           float (*cur)[2], float (*nxt)[2],
                                           int wv, int lane) {
    // halo reads (cur valid per previous barrier); same-address within a wave
    // -> LDS broadcast, no bank conflict
    float ldsL = cur[(wv + 3) & 3][1];
    float ldsR = cur[(wv + 1) & 3][0];
    float left  = __shfl_up(h[3], 1);    // prev lane's last row
    float right = __shfl_down(h[0], 1);  // next lane's first row
    if (lane == 0)  left  = ldsL;        // wave 0 edge: a[0]==0 kills garbage
    if (lane == 63) right = ldsR;        // wave 3 edge: c[1023]==0 kills garbage
    float n0 = fmaf(w.a.x, left, fmaf(w.b.x, h[0], w.c.x * h[1]));
    float n1 = fmaf(w.a.y, h[0], fmaf(w.b.y, h[1], w.c.y * h[2]));
    float n2 = fmaf(w.a.z, h[1], fmaf(w.b.z, h[2], w.c.z * h[3]));
    float n3 = fmaf(w.a.w, h[2], fmaf(w.b.w, h[3], w.c.w * right));
    h[0] = n0; h[1] = n1; h[2] = n2; h[3] = n3;
    // publish next layer's halo into the other parity buffer
    if (lane == 0)  nxt[wv][0] = h[0];
    if (lane == 63) nxt[wv][1] = h[3];
    lds_barrier();   // one LDS-scope barrier per layer; vmcnt stays outstanding
}

__global__ __launch_bounds__(256) void propagate(const float* __restrict__ x,
                                                 const float* __restrict__ wb,
                                                 float* __restrict__ out) {
    __shared__ float hal[2][4][2];
    const int b    = blockIdx.x;
    const int tid  = threadIdx.x;
    const int wv   = tid >> 6;
    const int lane = tid & 63;
    const int r0   = tid * 4;   // global row base for this lane

    float h[4];
    {
        float4 v = *reinterpret_cast<const float4*>(x + (size_t)b * NYP + r0);
        h[0] = v.x; h[1] = v.y; h[2] = v.z; h[3] = v.w;
    }

    W4 A, B, C, D;
    load_w(wb, 0, r0, A);
    load_w(wb, 1, r0, B);
    load_w(wb, 2, r0, C);

    // prologue: publish layer-0 halo
    if (lane == 0)  hal[0][wv][0] = h[0];
    if (lane == 63) hal[0][wv][1] = h[3];
    lds_barrier();

#pragma unroll 1
    for (int l = 0; l < NXL; l += 4) {   // halo parities per body: 0,1,0,1
        load_w(wb, (l + 3 < NXL) ? l + 3 : NXL - 1, r0, D);
        layer_step(h, A, hal[0], hal[1], wv, lane);
        load_w(wb, (l + 4 < NXL) ? l + 4 : NXL - 1, r0, A);
        layer_step(h, B, hal[1], hal[0], wv, lane);
        load_w(wb, (l + 5 < NXL) ? l + 5 : NXL - 1, r0, B);
        layer_step(h, C, hal[0], hal[1], wv, lane);
        load_w(wb, (l + 6 < NXL) ? l + 6 : NXL - 1, r0, C);
        layer_step(h, D, hal[1], hal[0], wv, lane);
    }

    *reinterpret_cast<float4*>(out + (size_t)b * NYP + r0) =
        make_float4(h[0], h[1], h[2], h[3]);
}

// ---------------- fallback: direct scattered weight reads (if ws too small) ----------------
__global__ __launch_bounds__(256) void propagate_direct(const float* __restrict__ x,
                                                        const float* __restrict__ W,
                                                        float* __restrict__ out) {
    __shared__ float hal[2][4][2];
    const int b    = blockIdx.x;
    const int tid  = threadIdx.x;
    const int wv   = tid >> 6;
    const int lane = tid & 63;
    const int r0   = tid * 4;

    float h[4];
    {
        float4 v = *reinterpret_cast<const float4*>(x + (size_t)b * NYP + r0);
        h[0] = v.x; h[1] = v.y; h[2] = v.z; h[3] = v.w;
    }

    if (lane == 0)  hal[0][wv][0] = h[0];
    if (lane == 63) hal[0][wv][1] = h[3];
    lds_barrier();

#pragma unroll 1
    for (int l = 0; l < NXL; ++l) {
        const float* Wl = W + ((size_t)l << 20);
        W4 w;
        float t[3][4];
#pragma unroll
        for (int k = 0; k < 4; ++k) {
            int i = r0 + k;
            const float* row = Wl + ((size_t)i << 10);
            t[0][k] = (i > 0)       ? row[i - 1] : 0.0f;
            t[1][k] = row[i];
            t[2][k] = (i < NYP - 1) ? row[i + 1] : 0.0f;
        }
        w.a = make_float4(t[0][0], t[0][1], t[0][2], t[0][3]);
        w.b = make_float4(t[1][0], t[1][1], t[1][2], t[1][3]);
        w.c = make_float4(t[2][0], t[2][1], t[2][2], t[2][3]);
        if (l & 1) layer_step(h, w, hal[1], hal[0], wv, lane);
        else       layer_step(h, w, hal[0], hal[1], wv, lane);
    }

    *reinterpret_cast<float4*>(out + (size_t)b * NYP + r0) =
        make_float4(h[0], h[1], h[2], h[3]);
}

extern "C" void kernel_launch(void* const* d_in, const int* in_sizes, int n_in,
                              void* d_out, int out_size, void* d_ws, size_t ws_size,
                              hipStream_t stream) {
    const float* x = (const float*)d_in[0];   // [256,1024] f32
    const float* W = (const float*)d_in[1];   // [128,1024,1024] f32
    float* out = (float*)d_out;               // [256,1024] f32

    const size_t need = (size_t)NXL * 3 * NYP * sizeof(float);  // 1.5 MB
    if (ws_size >= need) {
        float* wbp = (float*)d_ws;
        extract_band<<<(NXL * NYP) / 256, 256, 0, stream>>>(W, wbp);
        propagate<<<NB, 256, 0, stream>>>(x, wbp, out);
    } else {
        propagate_direct<<<NB, 256, 0, stream>>>(x, W, out);
    }
}

// Round 5
// 35.861 us; speedup vs baseline: 3.8436x; 1.2568x over previous
//
#include <hip/hip_runtime.h>
#include <hip/hip_bf16.h>

// RedistributionNetwork: 128 sequential tridiagonal layers on [256,1024] f32 state.
// h'[i] = a[i]*h[i-1] + b[i]*h[i] + c[i]*h[i+1]; off-band W entries are exactly 0
// (band_mask), so a[l][0]==0 and c[l][1023]==0 exactly -> edge garbage annihilated.

#define NXL 128   // layers
#define NYP 1024  // state width
#define NB  256   // batch

// ---------------- kernel 1: band extraction (bf16 output) ----------------
// W: [NXL][NYP][NYP] f32  ->  band: [NXL][3][NYP] bf16 (a, b, c rows per layer)
__global__ __launch_bounds__(256) void extract_band(const float* __restrict__ W,
                                                    __hip_bfloat16* __restrict__ band) {
    int idx = blockIdx.x * 256 + threadIdx.x;   // 0 .. NXL*NYP-1
    int l = idx >> 10;
    int i = idx & (NYP - 1);
    const float* row = W + ((size_t)l << 20) + ((size_t)i << 10);
    float a = (i > 0)       ? row[i - 1] : 0.0f;   // W[l,i,i-1]
    float b = row[i];                               // W[l,i,i]
    float c = (i < NYP - 1) ? row[i + 1] : 0.0f;   // W[l,i,i+1]
    __hip_bfloat16* dst = band + (size_t)l * (3 * NYP);
    dst[i]           = __float2bfloat16(a);
    dst[NYP + i]     = __float2bfloat16(b);
    dst[2 * NYP + i] = __float2bfloat16(c);
}

// ---------------- kernel 2: banded propagation (bf16 band) ----------------
// 256 blocks (one per batch elem) x 256 threads (4 waves). Lane owns 4 rows
// (base = tid*4). Intra-wave halo via shuffles; inter-wave halo via parity
// double-buffered LDS. Halo ds_read is issued RIGHT AFTER the barrier and
// consumed LAST next layer (interior FMAs first) to hide ~120cy LDS latency.
// LDS-only barrier (lgkmcnt(0) + s_barrier) keeps weight prefetch in flight.

struct WB16 { uint2 a, b, c; };   // 4 bf16 per diagonal (one lane's 4 rows)

__device__ __forceinline__ void load_w16(const __hip_bfloat16* __restrict__ band,
                                         int layer, int r0, WB16& w) {
    const __hip_bfloat16* wl = band + (size_t)layer * (3 * NYP);
    w.a = *reinterpret_cast<const uint2*>(wl + r0);
    w.b = *reinterpret_cast<const uint2*>(wl + NYP + r0);
    w.c = *reinterpret_cast<const uint2*>(wl + 2 * NYP + r0);
}

__device__ __forceinline__ float blo(unsigned u) { return __uint_as_float(u << 16); }
__device__ __forceinline__ float bhi(unsigned u) { return __uint_as_float(u & 0xffff0000u); }

// One layer. hl/hr are this layer's inter-wave halo values (read a layer ago);
// at the end we publish the new halo, barrier, and immediately issue the reads
// for the NEXT layer into hl/hr.
__device__ __forceinline__ void step16(float (&h)[4], const WB16& w,
                                       float (*nxt)[2], int wv, int lane,
                                       float& hl, float& hr) {
    float ax = blo(w.a.x), ay = bhi(w.a.x), az = blo(w.a.y), aw = bhi(w.a.y);
    float bx = blo(w.b.x), by = bhi(w.b.x), bz = blo(w.b.y), bw = bhi(w.b.y);
    float cx = blo(w.c.x), cy = bhi(w.c.x), cz = blo(w.c.y), cw = bhi(w.c.y);
    float left  = __shfl_up(h[3], 1);    // prev lane's last row
    float right = __shfl_down(h[0], 1);  // next lane's first row
    // interior rows first: no dependence on LDS halo -> scheduler can run these
    // while hl/hr (issued after the previous barrier) are still in flight
    float n1 = fmaf(ay, h[0], fmaf(by, h[1], cy * h[2]));
    float n2 = fmaf(az, h[1], fmaf(bz, h[2], cz * h[3]));
    float base0 = fmaf(bx, h[0], cx * h[1]);
    float base3 = fmaf(aw, h[2], bw * h[3]);
    // edge rows last; wave-0 lane-0 / wave-3 lane-63 garbage killed by exact-0 weights
    float n0 = fmaf(ax, (lane == 0)  ? hl : left,  base0);
    float n3 = fmaf(cw, (lane == 63) ? hr : right, base3);
    h[0] = n0; h[1] = n1; h[2] = n2; h[3] = n3;
    if (lane == 0)  nxt[wv][0] = n0;
    if (lane == 63) nxt[wv][1] = n3;
    asm volatile("s_waitcnt lgkmcnt(0)" ::: "memory");   // LDS-scope only
    __builtin_amdgcn_s_barrier();
    // issue next layer's halo reads NOW; consumed late in the next step16
    hl = nxt[(wv + 3) & 3][1];
    hr = nxt[(wv + 1) & 3][0];
}

__global__ __launch_bounds__(256) void propagate(const float* __restrict__ x,
                                                 const __hip_bfloat16* __restrict__ band,
                                                 float* __restrict__ out) {
    __shared__ float hal[2][4][2];
    const int b    = blockIdx.x;
    const int tid  = threadIdx.x;
    const int wv   = tid >> 6;
    const int lane = tid & 63;
    const int r0   = tid * 4;   // global row base for this lane

    float h[4];
    {
        float4 v = *reinterpret_cast<const float4*>(x + (size_t)b * NYP + r0);
        h[0] = v.x; h[1] = v.y; h[2] = v.z; h[3] = v.w;
    }

    WB16 A, B, C, D;
    load_w16(band, 0, r0, A);
    load_w16(band, 1, r0, B);
    load_w16(band, 2, r0, C);

    // prologue: publish layer-0 input halo into parity 0, then preload hl/hr
    if (lane == 0)  hal[0][wv][0] = h[0];
    if (lane == 63) hal[0][wv][1] = h[3];
    asm volatile("s_waitcnt lgkmcnt(0)" ::: "memory");
    __builtin_amdgcn_s_barrier();
    float hl = hal[0][(wv + 3) & 3][1];
    float hr = hal[0][(wv + 1) & 3][0];

#pragma unroll 1
    for (int l = 0; l < NXL; l += 4) {   // write parities per body: 1,0,1,0
        load_w16(band, (l + 3 < NXL) ? l + 3 : NXL - 1, r0, D);
        step16(h, A, hal[1], wv, lane, hl, hr);
        load_w16(band, (l + 4 < NXL) ? l + 4 : NXL - 1, r0, A);
        step16(h, B, hal[0], wv, lane, hl, hr);
        load_w16(band, (l + 5 < NXL) ? l + 5 : NXL - 1, r0, B);
        step16(h, C, hal[1], wv, lane, hl, hr);
        load_w16(band, (l + 6 < NXL) ? l + 6 : NXL - 1, r0, C);
        step16(h, D, hal[0], wv, lane, hl, hr);
    }

    *reinterpret_cast<float4*>(out + (size_t)b * NYP + r0) =
        make_float4(h[0], h[1], h[2], h[3]);
}

// ---------------- fallback: direct scattered f32 weight reads (ws too small) ----------------
struct W4 { float4 a, b, c; };

__device__ __forceinline__ void lds_barrier() {
    asm volatile("s_waitcnt lgkmcnt(0)" ::: "memory");
    __builtin_amdgcn_s_barrier();
}

__device__ __forceinline__ void layer_step(float (&h)[4], const W4& w,
                                           float (*cur)[2], float (*nxt)[2],
                                           int wv, int lane) {
    float ldsL = cur[(wv + 3) & 3][1];
    float ldsR = cur[(wv + 1) & 3][0];
    float left  = __shfl_up(h[3], 1);
    float right = __shfl_down(h[0], 1);
    if (lane == 0)  left  = ldsL;
    if (lane == 63) right = ldsR;
    float n0 = fmaf(w.a.x, left, fmaf(w.b.x, h[0], w.c.x * h[1]));
    float n1 = fmaf(w.a.y, h[0], fmaf(w.b.y, h[1], w.c.y * h[2]));
    float n2 = fmaf(w.a.z, h[1], fmaf(w.b.z, h[2], w.c.z * h[3]));
    float n3 = fmaf(w.a.w, h[2], fmaf(w.b.w, h[3], w.c.w * right));
    h[0] = n0; h[1] = n1; h[2] = n2; h[3] = n3;
    if (lane == 0)  nxt[wv][0] = h[0];
    if (lane == 63) nxt[wv][1] = h[3];
    lds_barrier();
}

__global__ __launch_bounds__(256) void propagate_direct(const float* __restrict__ x,
                                                        const float* __restrict__ W,
                                                        float* __restrict__ out) {
    __shared__ float hal[2][4][2];
    const int b    = blockIdx.x;
    const int tid  = threadIdx.x;
    const int wv   = tid >> 6;
    const int lane = tid & 63;
    const int r0   = tid * 4;

    float h[4];
    {
        float4 v = *reinterpret_cast<const float4*>(x + (size_t)b * NYP + r0);
        h[0] = v.x; h[1] = v.y; h[2] = v.z; h[3] = v.w;
    }

    if (lane == 0)  hal[0][wv][0] = h[0];
    if (lane == 63) hal[0][wv][1] = h[3];
    lds_barrier();

#pragma unroll 1
    for (int l = 0; l < NXL; ++l) {
        const float* Wl = W + ((size_t)l << 20);
        W4 w;
        float t[3][4];
#pragma unroll
        for (int k = 0; k < 4; ++k) {
            int i = r0 + k;
            const float* row = Wl + ((size_t)i << 10);
            t[0][k] = (i > 0)       ? row[i - 1] : 0.0f;
            t[1][k] = row[i];
            t[2][k] = (i < NYP - 1) ? row[i + 1] : 0.0f;
        }
        w.a = make_float4(t[0][0], t[0][1], t[0][2], t[0][3]);
        w.b = make_float4(t[1][0], t[1][1], t[1][2], t[1][3]);
        w.c = make_float4(t[2][0], t[2][1], t[2][2], t[2][3]);
        if (l & 1) layer_step(h, w, hal[1], hal[0], wv, lane);
        else       layer_step(h, w, hal[0], hal[1], wv, lane);
    }

    *reinterpret_cast<float4*>(out + (size_t)b * NYP + r0) =
        make_float4(h[0], h[1], h[2], h[3]);
}

extern "C" void kernel_launch(void* const* d_in, const int* in_sizes, int n_in,
                              void* d_out, int out_size, void* d_ws, size_t ws_size,
                              hipStream_t stream) {
    const float* x = (const float*)d_in[0];   // [256,1024] f32
    const float* W = (const float*)d_in[1];   // [128,1024,1024] f32
    float* out = (float*)d_out;               // [256,1024] f32

    const size_t need = (size_t)NXL * 3 * NYP * sizeof(__hip_bfloat16);  // 768 KB
    if (ws_size >= need) {
        __hip_bfloat16* band = (__hip_bfloat16*)d_ws;
        extract_band<<<(NXL * NYP) / 256, 256, 0, stream>>>(W, band);
        propagate<<<NB, 256, 0, stream>>>(x, band, out);
    } else {
        propagate_direct<<<NB, 256, 0, stream>>>(x, W, out);
    }
}

// Round 6
// 35.605 us; speedup vs baseline: 3.8712x; 1.0072x over previous
//
#include <hip/hip_runtime.h>
#include <hip/hip_bf16.h>

// RedistributionNetwork: 128 sequential tridiagonal layers on [256,1024] f32 state.
// Layers pre-composed in groups of 4: M_q = W[4q+3]·W[4q+2]·W[4q+1]·W[4q] is
// 9-diagonal. Propagation = 32 sequential 9-point stencil steps (4x less serial
// depth, fewer total MACs, fewer barriers than the per-layer tridiag sweep).

#define NXL 128   // layers
#define NYP 1024  // state width
#define NB  256   // batch
#define NQ  32    // quads

// ---- guarded tridiag coefficient loads from one W layer (band_mask semantics) ----
__device__ __forceinline__ float gA(const float* __restrict__ Wl, int r) {
    // a(r) = W[r][r-1]; a(0)==0 by mask, r<1 also avoids OOB read
    return (r >= 1 && r < NYP) ? Wl[(size_t)r * NYP + (r - 1)] : 0.0f;
}
__device__ __forceinline__ float gB(const float* __restrict__ Wl, int r) {
    return ((unsigned)r < NYP) ? Wl[(size_t)r * NYP + r] : 0.0f;
}
__device__ __forceinline__ float gC(const float* __restrict__ Wl, int r) {
    return (r >= 0 && r < NYP - 1) ? Wl[(size_t)r * NYP + (r + 1)] : 0.0f;
}

// ---------------- kernel 1: fused extract+compose ----------------
// band9[q][d][i] = M_q[i, i + d - 4], bf16, exact 0 outside the matrix.
// Row i of M_q built as row-vector p := e_i^T W3, then p := p·W2, p·W1, p·W0.
// Right-multiply: (p·W)[i+d] = p[i+d+1]·a(i+d+1) + p[i+d]·b(i+d) + p[i+d-1]·c(i+d-1).
__global__ __launch_bounds__(256) void compose_quads(const float* __restrict__ W,
                                                     __hip_bfloat16* __restrict__ band9) {
    int t = blockIdx.x * 256 + threadIdx.x;   // 0 .. NQ*NYP-1
    int q = t >> 10;
    int i = t & (NYP - 1);
    const float* W0 = W + ((size_t)(4 * q + 0) << 20);   // applied first
    const float* W1 = W + ((size_t)(4 * q + 1) << 20);
    const float* W2 = W + ((size_t)(4 * q + 2) << 20);
    const float* W3 = W + ((size_t)(4 * q + 3) << 20);   // applied last

    // p[d+5] holds column i+d; indices all compile-time after unroll (SROA-safe)
    float p[11], r[11];
#pragma unroll
    for (int k = 0; k < 11; ++k) { p[k] = 0.0f; r[k] = 0.0f; }
    p[4] = gA(W3, i); p[5] = gB(W3, i); p[6] = gC(W3, i);

    // x W2 : support -2..2
#pragma unroll
    for (int d = -2; d <= 2; ++d)
        r[d + 5] = fmaf(p[d + 6], gA(W2, i + d + 1),
                   fmaf(p[d + 5], gB(W2, i + d),
                        p[d + 4] * gC(W2, i + d - 1)));
#pragma unroll
    for (int k = 0; k < 11; ++k) p[k] = r[k];

    // x W1 : support -3..3
#pragma unroll
    for (int d = -3; d <= 3; ++d)
        r[d + 5] = fmaf(p[d + 6], gA(W1, i + d + 1),
                   fmaf(p[d + 5], gB(W1, i + d),
                        p[d + 4] * gC(W1, i + d - 1)));
#pragma unroll
    for (int k = 0; k < 11; ++k) p[k] = r[k];

    // x W0 : support -4..4
#pragma unroll
    for (int d = -4; d <= 4; ++d)
        r[d + 5] = fmaf(p[d + 6], gA(W0, i + d + 1),
                   fmaf(p[d + 5], gB(W0, i + d),
                        p[d + 4] * gC(W0, i + d - 1)));

    __hip_bfloat16* dst = band9 + (size_t)q * 9 * NYP + i;
#pragma unroll
    for (int d = 0; d < 9; ++d)
        dst[d * NYP] = __float2bfloat16(r[d + 1]);   // offset d-4 lives at r[(d-4)+5]
}

// ---------------- kernel 2: 9-diagonal propagation, 32 steps ----------------
// 256 blocks (one batch elem) x 256 threads (4 waves). Lane owns 4 rows
// (r0 = tid*4). Halo = neighbor lane's full 4-row block: shuffles intra-wave,
// parity double-buffered LDS at wave edges, LDS-only barrier per step.

struct B9u { uint2 d[9]; };   // 9 diagonals x 4 bf16 rows (accessed const-index only)

__device__ __forceinline__ void load9(const __hip_bfloat16* __restrict__ band9,
                                      int q, int r0, B9u& w) {
    const __hip_bfloat16* base = band9 + (size_t)q * 9 * NYP + r0;
#pragma unroll
    for (int d = 0; d < 9; ++d)
        w.d[d] = *reinterpret_cast<const uint2*>(base + d * NYP);
}

__device__ __forceinline__ float blo(unsigned u) { return __uint_as_float(u << 16); }
__device__ __forceinline__ float bhi(unsigned u) { return __uint_as_float(u & 0xffff0000u); }

__device__ __forceinline__ float wc(const B9u& w, int d, int j) {
    // d, j compile-time constants at every call site
    unsigned u = (j < 2) ? w.d[d].x : w.d[d].y;
    return (j & 1) ? bhi(u) : blo(u);
}

// One 9-point stencil step + halo exchange for the next step.
__device__ __forceinline__ void step9(float (&h)[4], const B9u& w,
                                      float (&hLds)[4], float (&hRds)[4],
                                      float (*nxt)[2][4], int wv, int lane) {
    float hl[4], hr[4];
#pragma unroll
    for (int j = 0; j < 4; ++j) {
        float su = __shfl_up(h[j], 1);     // prev lane's row r0-4+j
        float sd = __shfl_down(h[j], 1);   // next lane's row r0+4+j
        hl[j] = (lane == 0)  ? hLds[j] : su;   // wave edge from LDS
        hr[j] = (lane == 63) ? hRds[j] : sd;   // out-of-matrix killed by 0 coefs
    }
    float n[4];
#pragma unroll
    for (int j = 0; j < 4; ++j) {
        float acc = 0.0f;
        // interior terms first (pure-register), halo-dependent terms last
#pragma unroll
        for (int d = 0; d < 9; ++d)
            if (j + d >= 4 && j + d <= 7) acc = fmaf(wc(w, d, j), h[j + d - 4], acc);
#pragma unroll
        for (int d = 0; d < 9; ++d)
            if (j + d < 4) acc = fmaf(wc(w, d, j), hl[j + d], acc);
#pragma unroll
        for (int d = 0; d < 9; ++d)
            if (j + d > 7) acc = fmaf(wc(w, d, j), hr[j + d - 8], acc);
        n[j] = acc;
    }
#pragma unroll
    for (int j = 0; j < 4; ++j) h[j] = n[j];
    if (lane == 0) {
#pragma unroll
        for (int j = 0; j < 4; ++j) nxt[wv][0][j] = h[j];
    }
    if (lane == 63) {
#pragma unroll
        for (int j = 0; j < 4; ++j) nxt[wv][1][j] = h[j];
    }
    asm volatile("s_waitcnt lgkmcnt(0)" ::: "memory");   // LDS-scope barrier only:
    __builtin_amdgcn_s_barrier();                        // weight loads stay in flight
    // issue next step's halo reads now; consumed late next step
#pragma unroll
    for (int j = 0; j < 4; ++j) {
        hLds[j] = nxt[(wv + 3) & 3][1][j];
        hRds[j] = nxt[(wv + 1) & 3][0][j];
    }
}

__global__ __launch_bounds__(256) void propagate9(const float* __restrict__ x,
                                                  const __hip_bfloat16* __restrict__ band9,
                                                  float* __restrict__ out) {
    __shared__ float hal[2][4][2][4];   // [parity][wave][0=first4,1=last4][row]
    const int b    = blockIdx.x;
    const int tid  = threadIdx.x;
    const int wv   = tid >> 6;
    const int lane = tid & 63;
    const int r0   = tid * 4;

    float h[4];
    {
        float4 v = *reinterpret_cast<const float4*>(x + (size_t)b * NYP + r0);
        h[0] = v.x; h[1] = v.y; h[2] = v.z; h[3] = v.w;
    }

    B9u WA, WB;
    load9(band9, 0, r0, WA);

    // prologue: publish step-0 halo into parity 0
    if (lane == 0) {
#pragma unroll
        for (int j = 0; j < 4; ++j) hal[0][wv][0][j] = h[j];
    }
    if (lane == 63) {
#pragma unroll
        for (int j = 0; j < 4; ++j) hal[0][wv][1][j] = h[j];
    }
    asm volatile("s_waitcnt lgkmcnt(0)" ::: "memory");
    __builtin_amdgcn_s_barrier();
    float hLds[4], hRds[4];
#pragma unroll
    for (int j = 0; j < 4; ++j) {
        hLds[j] = hal[0][(wv + 3) & 3][1][j];
        hRds[j] = hal[0][(wv + 1) & 3][0][j];
    }

#pragma unroll 1
    for (int s = 0; s < NQ; s += 2) {
        load9(band9, (s + 1 < NQ) ? s + 1 : NQ - 1, r0, WB);
        step9(h, WA, hLds, hRds, hal[1], wv, lane);           // step s   (nxt parity 1)
        load9(band9, (s + 2 < NQ) ? s + 2 : NQ - 1, r0, WA);
        step9(h, WB, hLds, hRds, hal[0], wv, lane);           // step s+1 (nxt parity 0)
    }

    *reinterpret_cast<float4*>(out + (size_t)b * NYP + r0) =
        make_float4(h[0], h[1], h[2], h[3]);
}

// ---------------- fallback: direct tridiag sweep from W (ws too small) ----------------
struct W4 { float4 a, b, c; };

__device__ __forceinline__ void lds_barrier() {
    asm volatile("s_waitcnt lgkmcnt(0)" ::: "memory");
    __builtin_amdgcn_s_barrier();
}

__device__ __forceinline__ void layer_step(float (&h)[4], const W4& w,
                                           float (*cur)[2], float (*nxt)[2],
                                           int wv, int lane) {
    float ldsL = cur[(wv + 3) & 3][1];
    float ldsR = cur[(wv + 1) & 3][0];
    float left  = __shfl_up(h[3], 1);
    float right = __shfl_down(h[0], 1);
    if (lane == 0)  left  = ldsL;
    if (lane == 63) right = ldsR;
    float n0 = fmaf(w.a.x, left, fmaf(w.b.x, h[0], w.c.x * h[1]));
    float n1 = fmaf(w.a.y, h[0], fmaf(w.b.y, h[1], w.c.y * h[2]));
    float n2 = fmaf(w.a.z, h[1], fmaf(w.b.z, h[2], w.c.z * h[3]));
    float n3 = fmaf(w.a.w, h[2], fmaf(w.b.w, h[3], w.c.w * right));
    h[0] = n0; h[1] = n1; h[2] = n2; h[3] = n3;
    if (lane == 0)  nxt[wv][0] = h[0];
    if (lane == 63) nxt[wv][1] = h[3];
    lds_barrier();
}

__global__ __launch_bounds__(256) void propagate_direct(const float* __restrict__ x,
                                                        const float* __restrict__ W,
                                                        float* __restrict__ out) {
    __shared__ float hal[2][4][2];
    const int b    = blockIdx.x;
    const int tid  = threadIdx.x;
    const int wv   = tid >> 6;
    const int lane = tid & 63;
    const int r0   = tid * 4;

    float h[4];
    {
        float4 v = *reinterpret_cast<const float4*>(x + (size_t)b * NYP + r0);
        h[0] = v.x; h[1] = v.y; h[2] = v.z; h[3] = v.w;
    }

    if (lane == 0)  hal[0][wv][0] = h[0];
    if (lane == 63) hal[0][wv][1] = h[3];
    lds_barrier();

#pragma unroll 1
    for (int l = 0; l < NXL; ++l) {
        W4 w;
        float t0[4], t1[4], t2[4];
        const float* Wl = W + ((size_t)l << 20);
#pragma unroll
        for (int k = 0; k < 4; ++k) {
            int i = r0 + k;
            t0[k] = gA(Wl, i); t1[k] = gB(Wl, i); t2[k] = gC(Wl, i);
        }
        w.a = make_float4(t0[0], t0[1], t0[2], t0[3]);
        w.b = make_float4(t1[0], t1[1], t1[2], t1[3]);
        w.c = make_float4(t2[0], t2[1], t2[2], t2[3]);
        if (l & 1) layer_step(h, w, hal[1], hal[0], wv, lane);
        else       layer_step(h, w, hal[0], hal[1], wv, lane);
    }

    *reinterpret_cast<float4*>(out + (size_t)b * NYP + r0) =
        make_float4(h[0], h[1], h[2], h[3]);
}

extern "C" void kernel_launch(void* const* d_in, const int* in_sizes, int n_in,
                              void* d_out, int out_size, void* d_ws, size_t ws_size,
                              hipStream_t stream) {
    const float* x = (const float*)d_in[0];   // [256,1024] f32
    const float* W = (const float*)d_in[1];   // [128,1024,1024] f32
    float* out = (float*)d_out;               // [256,1024] f32

    const size_t need = (size_t)NQ * 9 * NYP * sizeof(__hip_bfloat16);  // 576 KB
    if (ws_size >= need) {
        __hip_bfloat16* band9 = (__hip_bfloat16*)d_ws;
        compose_quads<<<(NQ * NYP) / 256, 256, 0, stream>>>(W, band9);
        propagate9<<<NB, 256, 0, stream>>>(x, band9, out);
    } else {
        propagate_direct<<<NB, 256, 0, stream>>>(x, W, out);
    }
}

// Round 7
// 33.854 us; speedup vs baseline: 4.0715x; 1.0517x over previous
//
#include <hip/hip_runtime.h>
#include <hip/hip_bf16.h>

// RedistributionNetwork: 128 sequential tridiagonal layers on [256,1024] f32 state.
// Pipeline: (A) gather_tri: one dwordx4 per (layer,row) -> compact f32 tridiag
//           (B) compose_quads: 4-layer products (9-diagonal) from the COMPACT band
//           (C) propagate9: 32 nine-point stencil steps (identical to round 6)

#define NXL 128   // layers
#define NYP 1024  // state width
#define NB  256   // batch
#define NQ  32    // quads

// 4B-aligned float4 (rows are only dword-aligned at the diagonal)
struct __attribute__((packed, aligned(4))) f4u { float x, y, z, w; };

// ---------------- kernel A: minimal-request diagonal gather ----------------
// tri[l][0][i]=a=W[l,i,i-1], tri[l][1][i]=b=W[l,i,i], tri[l][2][i]=c=W[l,i,i+1]
__global__ __launch_bounds__(256) void gather_tri(const float* __restrict__ W,
                                                  float* __restrict__ tri) {
    int t = blockIdx.x * 256 + threadIdx.x;   // 0 .. NXL*NYP-1
    int l = t >> 10;
    int i = t & (NYP - 1);
    size_t base = ((size_t)l << 20) + (size_t)i * (NYP + 1);  // diag element index
    // one 16B load covers the 12 useful bytes; edge rows shift the window inward
    const float* lp = W + base + ((i == 0) ? 0 : (i == NYP - 1) ? -3 : -1);
    f4u v = *reinterpret_cast<const f4u*>(lp);
    float a, b, c;
    if (i == 0)            { a = 0.0f; b = v.x; c = v.y; }        // cols 0..3
    else if (i == NYP - 1) { a = v.z;  b = v.w; c = 0.0f; }       // cols i-3..i
    else                   { a = v.x;  b = v.y; c = v.z; }        // cols i-1..i+2
    float* dst = tri + (size_t)l * (3 * NYP);
    dst[i]           = a;
    dst[NYP + i]     = b;
    dst[2 * NYP + i] = c;
}

// ---------------- kernel B: compose quads from the compact band ----------------
// band9[q][d][i] = M_q[i, i+d-4] (bf16), M_q = W[4q+3]·W[4q+2]·W[4q+1]·W[4q].
// All reads hit the 1.5MB L2-resident tri. Guarded by unsigned range check;
// tri already stores exact 0 at a[0] and c[1023].
__device__ __forceinline__ float ga(const float* t, int r) {
    return ((unsigned)r < NYP) ? t[r] : 0.0f;
}
__device__ __forceinline__ float gb(const float* t, int r) {
    return ((unsigned)r < NYP) ? t[NYP + r] : 0.0f;
}
__device__ __forceinline__ float gc(const float* t, int r) {
    return ((unsigned)r < NYP) ? t[2 * NYP + r] : 0.0f;
}

__global__ __launch_bounds__(256) void compose_quads(const float* __restrict__ tri,
                                                     __hip_bfloat16* __restrict__ band9) {
    int t = blockIdx.x * 256 + threadIdx.x;   // 0 .. NQ*NYP-1
    int q = t >> 10;
    int i = t & (NYP - 1);
    const float* T0 = tri + (size_t)(4 * q + 0) * (3 * NYP);   // applied first
    const float* T1 = tri + (size_t)(4 * q + 1) * (3 * NYP);
    const float* T2 = tri + (size_t)(4 * q + 2) * (3 * NYP);
    const float* T3 = tri + (size_t)(4 * q + 3) * (3 * NYP);   // applied last

    // p[d+5] holds column i+d of the row-vector; all indices compile-time
    float p[11], r[11];
#pragma unroll
    for (int k = 0; k < 11; ++k) { p[k] = 0.0f; r[k] = 0.0f; }
    p[4] = ga(T3, i); p[5] = gb(T3, i); p[6] = gc(T3, i);   // e_i^T W3

    // (p·W)[c] = p[c+1]·a(c+1) + p[c]·b(c) + p[c-1]·c(c-1)
#pragma unroll
    for (int d = -2; d <= 2; ++d)
        r[d + 5] = fmaf(p[d + 6], ga(T2, i + d + 1),
                   fmaf(p[d + 5], gb(T2, i + d),
                        p[d + 4] * gc(T2, i + d - 1)));
#pragma unroll
    for (int k = 0; k < 11; ++k) p[k] = r[k];

#pragma unroll
    for (int d = -3; d <= 3; ++d)
        r[d + 5] = fmaf(p[d + 6], ga(T1, i + d + 1),
                   fmaf(p[d + 5], gb(T1, i + d),
                        p[d + 4] * gc(T1, i + d - 1)));
#pragma unroll
    for (int k = 0; k < 11; ++k) p[k] = r[k];

#pragma unroll
    for (int d = -4; d <= 4; ++d)
        r[d + 5] = fmaf(p[d + 6], ga(T0, i + d + 1),
                   fmaf(p[d + 5], gb(T0, i + d),
                        p[d + 4] * gc(T0, i + d - 1)));

    __hip_bfloat16* dst = band9 + (size_t)q * 9 * NYP + i;
#pragma unroll
    for (int d = 0; d < 9; ++d)
        dst[d * NYP] = __float2bfloat16(r[d + 1]);   // offset d-4 lives at r[(d-4)+5]
}

// ---------------- kernel C: 9-diagonal propagation (identical to round 6) ----------------
struct B9u { uint2 d[9]; };

__device__ __forceinline__ void load9(const __hip_bfloat16* __restrict__ band9,
                                      int q, int r0, B9u& w) {
    const __hip_bfloat16* base = band9 + (size_t)q * 9 * NYP + r0;
#pragma unroll
    for (int d = 0; d < 9; ++d)
        w.d[d] = *reinterpret_cast<const uint2*>(base + d * NYP);
}

__device__ __forceinline__ float blo(unsigned u) { return __uint_as_float(u << 16); }
__device__ __forceinline__ float bhi(unsigned u) { return __uint_as_float(u & 0xffff0000u); }

__device__ __forceinline__ float wc(const B9u& w, int d, int j) {
    unsigned u = (j < 2) ? w.d[d].x : w.d[d].y;
    return (j & 1) ? bhi(u) : blo(u);
}

__device__ __forceinline__ void step9(float (&h)[4], const B9u& w,
                                      float (&hLds)[4], float (&hRds)[4],
                                      float (*nxt)[2][4], int wv, int lane) {
    float hl[4], hr[4];
#pragma unroll
    for (int j = 0; j < 4; ++j) {
        float su = __shfl_up(h[j], 1);
        float sd = __shfl_down(h[j], 1);
        hl[j] = (lane == 0)  ? hLds[j] : su;
        hr[j] = (lane == 63) ? hRds[j] : sd;
    }
    float n[4];
#pragma unroll
    for (int j = 0; j < 4; ++j) {
        float acc = 0.0f;
#pragma unroll
        for (int d = 0; d < 9; ++d)
            if (j + d >= 4 && j + d <= 7) acc = fmaf(wc(w, d, j), h[j + d - 4], acc);
#pragma unroll
        for (int d = 0; d < 9; ++d)
            if (j + d < 4) acc = fmaf(wc(w, d, j), hl[j + d], acc);
#pragma unroll
        for (int d = 0; d < 9; ++d)
            if (j + d > 7) acc = fmaf(wc(w, d, j), hr[j + d - 8], acc);
        n[j] = acc;
    }
#pragma unroll
    for (int j = 0; j < 4; ++j) h[j] = n[j];
    if (lane == 0) {
#pragma unroll
        for (int j = 0; j < 4; ++j) nxt[wv][0][j] = h[j];
    }
    if (lane == 63) {
#pragma unroll
        for (int j = 0; j < 4; ++j) nxt[wv][1][j] = h[j];
    }
    asm volatile("s_waitcnt lgkmcnt(0)" ::: "memory");
    __builtin_amdgcn_s_barrier();
#pragma unroll
    for (int j = 0; j < 4; ++j) {
        hLds[j] = nxt[(wv + 3) & 3][1][j];
        hRds[j] = nxt[(wv + 1) & 3][0][j];
    }
}

__global__ __launch_bounds__(256) void propagate9(const float* __restrict__ x,
                                                  const __hip_bfloat16* __restrict__ band9,
                                                  float* __restrict__ out) {
    __shared__ float hal[2][4][2][4];
    const int b    = blockIdx.x;
    const int tid  = threadIdx.x;
    const int wv   = tid >> 6;
    const int lane = tid & 63;
    const int r0   = tid * 4;

    float h[4];
    {
        float4 v = *reinterpret_cast<const float4*>(x + (size_t)b * NYP + r0);
        h[0] = v.x; h[1] = v.y; h[2] = v.z; h[3] = v.w;
    }

    B9u WA, WB;
    load9(band9, 0, r0, WA);

    if (lane == 0) {
#pragma unroll
        for (int j = 0; j < 4; ++j) hal[0][wv][0][j] = h[j];
    }
    if (lane == 63) {
#pragma unroll
        for (int j = 0; j < 4; ++j) hal[0][wv][1][j] = h[j];
    }
    asm volatile("s_waitcnt lgkmcnt(0)" ::: "memory");
    __builtin_amdgcn_s_barrier();
    float hLds[4], hRds[4];
#pragma unroll
    for (int j = 0; j < 4; ++j) {
        hLds[j] = hal[0][(wv + 3) & 3][1][j];
        hRds[j] = hal[0][(wv + 1) & 3][0][j];
    }

#pragma unroll 1
    for (int s = 0; s < NQ; s += 2) {
        load9(band9, (s + 1 < NQ) ? s + 1 : NQ - 1, r0, WB);
        step9(h, WA, hLds, hRds, hal[1], wv, lane);
        load9(band9, (s + 2 < NQ) ? s + 2 : NQ - 1, r0, WA);
        step9(h, WB, hLds, hRds, hal[0], wv, lane);
    }

    *reinterpret_cast<float4*>(out + (size_t)b * NYP + r0) =
        make_float4(h[0], h[1], h[2], h[3]);
}

// ---------------- fallback: direct tridiag sweep from W (ws too small) ----------------
__device__ __forceinline__ float gAw(const float* __restrict__ Wl, int r) {
    return (r >= 1 && r < NYP) ? Wl[(size_t)r * NYP + (r - 1)] : 0.0f;
}
__device__ __forceinline__ float gBw(const float* __restrict__ Wl, int r) {
    return ((unsigned)r < NYP) ? Wl[(size_t)r * NYP + r] : 0.0f;
}
__device__ __forceinline__ float gCw(const float* __restrict__ Wl, int r) {
    return (r >= 0 && r < NYP - 1) ? Wl[(size_t)r * NYP + (r + 1)] : 0.0f;
}

struct W4 { float4 a, b, c; };

__device__ __forceinline__ void lds_barrier() {
    asm volatile("s_waitcnt lgkmcnt(0)" ::: "memory");
    __builtin_amdgcn_s_barrier();
}

__device__ __forceinline__ void layer_step(float (&h)[4], const W4& w,
                                           float (*cur)[2], float (*nxt)[2],
                                           int wv, int lane) {
    float ldsL = cur[(wv + 3) & 3][1];
    float ldsR = cur[(wv + 1) & 3][0];
    float left  = __shfl_up(h[3], 1);
    float right = __shfl_down(h[0], 1);
    if (lane == 0)  left  = ldsL;
    if (lane == 63) right = ldsR;
    float n0 = fmaf(w.a.x, left, fmaf(w.b.x, h[0], w.c.x * h[1]));
    float n1 = fmaf(w.a.y, h[0], fmaf(w.b.y, h[1], w.c.y * h[2]));
    float n2 = fmaf(w.a.z, h[1], fmaf(w.b.z, h[2], w.c.z * h[3]));
    float n3 = fmaf(w.a.w, h[2], fmaf(w.b.w, h[3], w.c.w * right));
    h[0] = n0; h[1] = n1; h[2] = n2; h[3] = n3;
    if (lane == 0)  nxt[wv][0] = h[0];
    if (lane == 63) nxt[wv][1] = h[3];
    lds_barrier();
}

__global__ __launch_bounds__(256) void propagate_direct(const float* __restrict__ x,
                                                        const float* __restrict__ W,
                                                        float* __restrict__ out) {
    __shared__ float hal[2][4][2];
    const int b    = blockIdx.x;
    const int tid  = threadIdx.x;
    const int wv   = tid >> 6;
    const int lane = tid & 63;
    const int r0   = tid * 4;

    float h[4];
    {
        float4 v = *reinterpret_cast<const float4*>(x + (size_t)b * NYP + r0);
        h[0] = v.x; h[1] = v.y; h[2] = v.z; h[3] = v.w;
    }

    if (lane == 0)  hal[0][wv][0] = h[0];
    if (lane == 63) hal[0][wv][1] = h[3];
    lds_barrier();

#pragma unroll 1
    for (int l = 0; l < NXL; ++l) {
        W4 w;
        float t0[4], t1[4], t2[4];
        const float* Wl = W + ((size_t)l << 20);
#pragma unroll
        for (int k = 0; k < 4; ++k) {
            int i = r0 + k;
            t0[k] = gAw(Wl, i); t1[k] = gBw(Wl, i); t2[k] = gCw(Wl, i);
        }
        w.a = make_float4(t0[0], t0[1], t0[2], t0[3]);
        w.b = make_float4(t1[0], t1[1], t1[2], t1[3]);
        w.c = make_float4(t2[0], t2[1], t2[2], t2[3]);
        if (l & 1) layer_step(h, w, hal[1], hal[0], wv, lane);
        else       layer_step(h, w, hal[0], hal[1], wv, lane);
    }

    *reinterpret_cast<float4*>(out + (size_t)b * NYP + r0) =
        make_float4(h[0], h[1], h[2], h[3]);
}

extern "C" void kernel_launch(void* const* d_in, const int* in_sizes, int n_in,
                              void* d_out, int out_size, void* d_ws, size_t ws_size,
                              hipStream_t stream) {
    const float* x = (const float*)d_in[0];   // [256,1024] f32
    const float* W = (const float*)d_in[1];   // [128,1024,1024] f32
    float* out = (float*)d_out;               // [256,1024] f32

    const size_t triBytes   = (size_t)NXL * 3 * NYP * sizeof(float);          // 1.5 MB
    const size_t band9Bytes = (size_t)NQ * 9 * NYP * sizeof(__hip_bfloat16);  // 576 KB
    if (ws_size >= triBytes + band9Bytes) {
        float* tri = (float*)d_ws;
        __hip_bfloat16* band9 = (__hip_bfloat16*)((char*)d_ws + triBytes);
        gather_tri<<<(NXL * NYP) / 256, 256, 0, stream>>>(W, tri);
        compose_quads<<<(NQ * NYP) / 256, 256, 0, stream>>>(tri, band9);
        propagate9<<<NB, 256, 0, stream>>>(x, band9, out);
    } else {
        propagate_direct<<<NB, 256, 0, stream>>>(x, W, out);
    }
}

// Round 8
// 29.473 us; speedup vs baseline: 4.6766x; 1.1486x over previous
//
#include <hip/hip_runtime.h>
#include <hip/hip_bf16.h>

// RedistributionNetwork: 128 sequential tridiagonal layers on [256,1024] f32 state.
// Pipeline (2 kernels):
//  (A) gather_compose: per (quad, 128-row slice), gather the 4 layers' tridiag
//      rows (one dwordx4 per row -> minimal line-misses, 256 blocks = full-chip
//      MSHR spread) into LDS, compose the 4-layer product's 9 diagonals, write
//      bf16 band9. Eliminates the round-7 tri global round-trip + one launch.
//  (B) propagate9: 32 nine-point stencil steps (identical to round 7).

#define NXL 128   // layers
#define NYP 1024  // state width
#define NB  256   // batch
#define NQ  32    // quads
#define SL  128   // output rows per compose block
#define HR  136   // gathered rows per layer per block (SL + 8 halo)

// 4B-aligned float4 (band rows are only dword-aligned)
struct __attribute__((packed, aligned(4))) f4u { float x, y, z, w; };

// ---------------- kernel A: fused gather + compose ----------------
// band9[q][d][i] = M_q[i, i+d-4] (bf16), M_q = W[4q+3]·W[4q+2]·W[4q+1]·W[4q].
__global__ __launch_bounds__(256) void gather_compose(const float* __restrict__ W,
                                                      __hip_bfloat16* __restrict__ band9) {
    __shared__ float ta[4][3][HR];   // [layer][a,b,c][local row]
    const int blk = blockIdx.x;      // 0..255
    const int q   = blk >> 3;
    const int s   = blk & 7;
    const int i0  = s * SL;          // output rows [i0, i0+SL)
    const int tid = threadIdx.x;

    // gather 4*HR = 544 rows; thread handles g = tid, tid+256, tid+512
#pragma unroll
    for (int g = tid; g < 4 * HR; g += 256) {
        int ly = g / HR;             // 0..3 (compile-time magic-div)
        int rr = g - ly * HR;        // 0..135
        int i  = i0 - 4 + rr;        // global row, may be out of range
        float a = 0.0f, b = 0.0f, c = 0.0f;
        if ((unsigned)i < NYP) {
            size_t base = ((size_t)(4 * q + ly) << 20) + (size_t)i * (NYP + 1);
            const float* lp = W + base + ((i == 0) ? 0 : (i == NYP - 1) ? -3 : -1);
            f4u v = *reinterpret_cast<const f4u*>(lp);
            if (i == 0)            { a = 0.0f; b = v.x; c = v.y; }
            else if (i == NYP - 1) { a = v.z;  b = v.w; c = 0.0f; }
            else                   { a = v.x;  b = v.y; c = v.z; }
        }
        ta[ly][0][rr] = a;
        ta[ly][1][rr] = b;
        ta[ly][2][rr] = c;
    }
    __syncthreads();

    if (tid < SL) {
        const int i  = i0 + tid;     // output row
        const int li = tid + 4;      // LDS index of column i (col c -> li + (c-i))
        // p[d+5] = row-vector coefficient at column i+d; all indices compile-time
        float p[11], r[11];
#pragma unroll
        for (int k = 0; k < 11; ++k) { p[k] = 0.0f; r[k] = 0.0f; }
        p[4] = ta[3][0][li]; p[5] = ta[3][1][li]; p[6] = ta[3][2][li];  // e_i^T W3

        // (p·W)[c] = p[c+1]·a(c+1) + p[c]·b(c) + p[c-1]·c(c-1); LDS idx = li + d
#pragma unroll
        for (int d = -2; d <= 2; ++d)
            r[d + 5] = fmaf(p[d + 6], ta[2][0][li + d + 1],
                       fmaf(p[d + 5], ta[2][1][li + d],
                            p[d + 4] * ta[2][2][li + d - 1]));
#pragma unroll
        for (int k = 0; k < 11; ++k) p[k] = r[k];

#pragma unroll
        for (int d = -3; d <= 3; ++d)
            r[d + 5] = fmaf(p[d + 6], ta[1][0][li + d + 1],
                       fmaf(p[d + 5], ta[1][1][li + d],
                            p[d + 4] * ta[1][2][li + d - 1]));
#pragma unroll
        for (int k = 0; k < 11; ++k) p[k] = r[k];

#pragma unroll
        for (int d = -4; d <= 4; ++d)
            r[d + 5] = fmaf(p[d + 6], ta[0][0][li + d + 1],
                       fmaf(p[d + 5], ta[0][1][li + d],
                            p[d + 4] * ta[0][2][li + d - 1]));

        __hip_bfloat16* dst = band9 + (size_t)q * 9 * NYP + i;
#pragma unroll
        for (int d = 0; d < 9; ++d)
            dst[d * NYP] = __float2bfloat16(r[d + 1]);   // offset d-4 at r[(d-4)+5]
    }
}

// ---------------- kernel B: 9-diagonal propagation (identical to round 7) ----------------
struct B9u { uint2 d[9]; };

__device__ __forceinline__ void load9(const __hip_bfloat16* __restrict__ band9,
                                      int q, int r0, B9u& w) {
    const __hip_bfloat16* base = band9 + (size_t)q * 9 * NYP + r0;
#pragma unroll
    for (int d = 0; d < 9; ++d)
        w.d[d] = *reinterpret_cast<const uint2*>(base + d * NYP);
}

__device__ __forceinline__ float blo(unsigned u) { return __uint_as_float(u << 16); }
__device__ __forceinline__ float bhi(unsigned u) { return __uint_as_float(u & 0xffff0000u); }

__device__ __forceinline__ float wc(const B9u& w, int d, int j) {
    unsigned u = (j < 2) ? w.d[d].x : w.d[d].y;
    return (j & 1) ? bhi(u) : blo(u);
}

__device__ __forceinline__ void step9(float (&h)[4], const B9u& w,
                                      float (&hLds)[4], float (&hRds)[4],
                                      float (*nxt)[2][4], int wv, int lane) {
    float hl[4], hr[4];
#pragma unroll
    for (int j = 0; j < 4; ++j) {
        float su = __shfl_up(h[j], 1);
        float sd = __shfl_down(h[j], 1);
        hl[j] = (lane == 0)  ? hLds[j] : su;
        hr[j] = (lane == 63) ? hRds[j] : sd;
    }
    float n[4];
#pragma unroll
    for (int j = 0; j < 4; ++j) {
        float acc = 0.0f;
#pragma unroll
        for (int d = 0; d < 9; ++d)
            if (j + d >= 4 && j + d <= 7) acc = fmaf(wc(w, d, j), h[j + d - 4], acc);
#pragma unroll
        for (int d = 0; d < 9; ++d)
            if (j + d < 4) acc = fmaf(wc(w, d, j), hl[j + d], acc);
#pragma unroll
        for (int d = 0; d < 9; ++d)
            if (j + d > 7) acc = fmaf(wc(w, d, j), hr[j + d - 8], acc);
        n[j] = acc;
    }
#pragma unroll
    for (int j = 0; j < 4; ++j) h[j] = n[j];
    if (lane == 0) {
#pragma unroll
        for (int j = 0; j < 4; ++j) nxt[wv][0][j] = h[j];
    }
    if (lane == 63) {
#pragma unroll
        for (int j = 0; j < 4; ++j) nxt[wv][1][j] = h[j];
    }
    asm volatile("s_waitcnt lgkmcnt(0)" ::: "memory");
    __builtin_amdgcn_s_barrier();
#pragma unroll
    for (int j = 0; j < 4; ++j) {
        hLds[j] = nxt[(wv + 3) & 3][1][j];
        hRds[j] = nxt[(wv + 1) & 3][0][j];
    }
}

__global__ __launch_bounds__(256) void propagate9(const float* __restrict__ x,
                                                  const __hip_bfloat16* __restrict__ band9,
                                                  float* __restrict__ out) {
    __shared__ float hal[2][4][2][4];
    const int b    = blockIdx.x;
    const int tid  = threadIdx.x;
    const int wv   = tid >> 6;
    const int lane = tid & 63;
    const int r0   = tid * 4;

    float h[4];
    {
        float4 v = *reinterpret_cast<const float4*>(x + (size_t)b * NYP + r0);
        h[0] = v.x; h[1] = v.y; h[2] = v.z; h[3] = v.w;
    }

    B9u WA, WB;
    load9(band9, 0, r0, WA);

    if (lane == 0) {
#pragma unroll
        for (int j = 0; j < 4; ++j) hal[0][wv][0][j] = h[j];
    }
    if (lane == 63) {
#pragma unroll
        for (int j = 0; j < 4; ++j) hal[0][wv][1][j] = h[j];
    }
    asm volatile("s_waitcnt lgkmcnt(0)" ::: "memory");
    __builtin_amdgcn_s_barrier();
    float hLds[4], hRds[4];
#pragma unroll
    for (int j = 0; j < 4; ++j) {
        hLds[j] = hal[0][(wv + 3) & 3][1][j];
        hRds[j] = hal[0][(wv + 1) & 3][0][j];
    }

#pragma unroll 1
    for (int s = 0; s < NQ; s += 2) {
        load9(band9, (s + 1 < NQ) ? s + 1 : NQ - 1, r0, WB);
        step9(h, WA, hLds, hRds, hal[1], wv, lane);
        load9(band9, (s + 2 < NQ) ? s + 2 : NQ - 1, r0, WA);
        step9(h, WB, hLds, hRds, hal[0], wv, lane);
    }

    *reinterpret_cast<float4*>(out + (size_t)b * NYP + r0) =
        make_float4(h[0], h[1], h[2], h[3]);
}

// ---------------- fallback: direct tridiag sweep from W (ws too small) ----------------
__device__ __forceinline__ float gAw(const float* __restrict__ Wl, int r) {
    return (r >= 1 && r < NYP) ? Wl[(size_t)r * NYP + (r - 1)] : 0.0f;
}
__device__ __forceinline__ float gBw(const float* __restrict__ Wl, int r) {
    return ((unsigned)r < NYP) ? Wl[(size_t)r * NYP + r] : 0.0f;
}
__device__ __forceinline__ float gCw(const float* __restrict__ Wl, int r) {
    return (r >= 0 && r < NYP - 1) ? Wl[(size_t)r * NYP + (r + 1)] : 0.0f;
}

struct W4 { float4 a, b, c; };

__device__ __forceinline__ void lds_barrier() {
    asm volatile("s_waitcnt lgkmcnt(0)" ::: "memory");
    __builtin_amdgcn_s_barrier();
}

__device__ __forceinline__ void layer_step(float (&h)[4], const W4& w,
                                           float (*cur)[2], float (*nxt)[2],
                                           int wv, int lane) {
    float ldsL = cur[(wv + 3) & 3][1];
    float ldsR = cur[(wv + 1) & 3][0];
    float left  = __shfl_up(h[3], 1);
    float right = __shfl_down(h[0], 1);
    if (lane == 0)  left  = ldsL;
    if (lane == 63) right = ldsR;
    float n0 = fmaf(w.a.x, left, fmaf(w.b.x, h[0], w.c.x * h[1]));
    float n1 = fmaf(w.a.y, h[0], fmaf(w.b.y, h[1], w.c.y * h[2]));
    float n2 = fmaf(w.a.z, h[1], fmaf(w.b.z, h[2], w.c.z * h[3]));
    float n3 = fmaf(w.a.w, h[2], fmaf(w.b.w, h[3], w.c.w * right));
    h[0] = n0; h[1] = n1; h[2] = n2; h[3] = n3;
    if (lane == 0)  nxt[wv][0] = h[0];
    if (lane == 63) nxt[wv][1] = h[3];
    lds_barrier();
}

__global__ __launch_bounds__(256) void propagate_direct(const float* __restrict__ x,
                                                        const float* __restrict__ W,
                                                        float* __restrict__ out) {
    __shared__ float hal[2][4][2];
    const int b    = blockIdx.x;
    const int tid  = threadIdx.x;
    const int wv   = tid >> 6;
    const int lane = tid & 63;
    const int r0   = tid * 4;

    float h[4];
    {
        float4 v = *reinterpret_cast<const float4*>(x + (size_t)b * NYP + r0);
        h[0] = v.x; h[1] = v.y; h[2] = v.z; h[3] = v.w;
    }

    if (lane == 0)  hal[0][wv][0] = h[0];
    if (lane == 63) hal[0][wv][1] = h[3];
    lds_barrier();

#pragma unroll 1
    for (int l = 0; l < NXL; ++l) {
        W4 w;
        float t0[4], t1[4], t2[4];
        const float* Wl = W + ((size_t)l << 20);
#pragma unroll
        for (int k = 0; k < 4; ++k) {
            int i = r0 + k;
            t0[k] = gAw(Wl, i); t1[k] = gBw(Wl, i); t2[k] = gCw(Wl, i);
        }
        w.a = make_float4(t0[0], t0[1], t0[2], t0[3]);
        w.b = make_float4(t1[0], t1[1], t1[2], t1[3]);
        w.c = make_float4(t2[0], t2[1], t2[2], t2[3]);
        if (l & 1) layer_step(h, w, hal[1], hal[0], wv, lane);
        else       layer_step(h, w, hal[0], hal[1], wv, lane);
    }

    *reinterpret_cast<float4*>(out + (size_t)b * NYP + r0) =
        make_float4(h[0], h[1], h[2], h[3]);
}

extern "C" void kernel_launch(void* const* d_in, const int* in_sizes, int n_in,
                              void* d_out, int out_size, void* d_ws, size_t ws_size,
                              hipStream_t stream) {
    const float* x = (const float*)d_in[0];   // [256,1024] f32
    const float* W = (const float*)d_in[1];   // [128,1024,1024] f32
    float* out = (float*)d_out;               // [256,1024] f32

    const size_t band9Bytes = (size_t)NQ * 9 * NYP * sizeof(__hip_bfloat16);  // 576 KB
    if (ws_size >= band9Bytes) {
        __hip_bfloat16* band9 = (__hip_bfloat16*)d_ws;
        gather_compose<<<NQ * 8, 256, 0, stream>>>(W, band9);
        propagate9<<<NB, 256, 0, stream>>>(x, band9, out);
    } else {
        propagate_direct<<<NB, 256, 0, stream>>>(x, W, out);
    }
}